// Round 15
// baseline (438.166 us; speedup 1.0000x reference)
//
#include <hip/hip_runtime.h>
#include <math.h>

#define NN   13
#define HH   128
#define NL   8
#define NJ   17
#define OBSD 348
#define DMAX 33
#define TB   8
#define NTHR 1024
#define ASTRIDE 256   // shorts per A row = 512 B; unit-swizzled (R8/R11-validated)
#define HSTRIDE 128   // same row viewed as fp32
#define HBS  136      // hb row stride in shorts (272 B; bank-spread, 16B-aligned)

// FEAT_IDX table (13 x 33), pad = -1
__constant__ int c_feat[NN * DMAX] = {
  0,1,2,3,4,22,23,24,25,26,27,45,46,47,48,49,50,51,52,53,54,175,176,177,178,179,180,270,271,272,273,274,275,
  5,6,28,29,55,56,57,58,59,60,61,62,63,64,181,182,183,184,185,186,276,277,278,279,280,281,-1,-1,-1,-1,-1,-1,-1,
  7,30,65,66,67,68,69,70,71,72,73,74,187,188,189,190,191,192,253,254,255,282,283,284,285,286,287,-1,-1,-1,-1,-1,-1,
  8,9,10,11,31,32,33,34,75,76,77,78,79,80,81,82,83,84,193,194,195,196,197,198,256,257,258,288,289,290,291,292,293,
  11,34,85,86,87,88,89,90,91,92,93,94,199,200,201,202,203,204,259,294,295,296,297,298,299,-1,-1,-1,-1,-1,-1,-1,-1,
  95,96,97,98,99,100,101,102,103,104,205,206,207,208,209,210,300,301,302,303,304,305,-1,-1,-1,-1,-1,-1,-1,-1,-1,-1,-1,
  12,13,14,15,35,36,37,38,105,106,107,108,109,110,111,112,113,114,211,212,213,214,215,216,260,261,262,306,307,308,309,310,311,
  15,38,115,116,117,118,119,120,121,122,123,124,217,218,219,220,221,222,263,312,313,314,315,316,317,-1,-1,-1,-1,-1,-1,-1,-1,
  125,126,127,128,129,130,131,132,133,134,223,224,225,226,227,228,318,319,320,321,322,323,-1,-1,-1,-1,-1,-1,-1,-1,-1,-1,-1,
  16,17,18,39,40,41,135,136,137,138,139,140,141,142,143,144,229,230,231,232,233,234,264,265,324,325,326,327,328,329,-1,-1,-1,
  18,41,145,146,147,148,149,150,151,152,153,154,235,236,237,238,239,240,266,330,331,332,333,334,335,-1,-1,-1,-1,-1,-1,-1,-1,
  19,20,21,42,43,44,155,156,157,158,159,160,161,162,163,164,241,242,243,244,245,246,267,268,336,337,338,339,340,341,-1,-1,-1,
  21,44,165,166,167,168,169,170,171,172,173,174,247,248,249,250,251,252,269,342,343,344,345,346,347,-1,-1,-1,-1,-1,-1,-1,-1
};

__device__ constexpr int ADJ[NN][3] = {
  {1,9,11},{0,2,0},{1,3,6},{2,4,0},{3,5,0},{4,0,0},{2,7,0},
  {6,8,0},{7,0,0},{0,10,0},{9,0,0},{0,12,0},{11,0,0}
};
__device__ constexpr int DEG[NN] = {3,2,3,2,2,1,2,2,1,2,1,2,1};
__device__ constexpr int JM0[NJ] = {1,1,1,2,2,2,3,2,2,2,6,0,0,9,0,0,11};
__device__ constexpr int JM1[NJ] = {2,2,2,3,3,3,4,6,6,6,7,9,9,10,11,11,12};

typedef float4 F4;
using h8v = __attribute__((ext_vector_type(8))) _Float16;  // 8 fp16 (4 VGPR)
using h2v = __attribute__((ext_vector_type(2))) _Float16;  // packed half2
using f32x4  = __attribute__((ext_vector_type(4)))  float; // MFMA 16x16 C/D
using f32x16 = __attribute__((ext_vector_type(16))) float; // MFMA 32x32 C/D

// elu: for v<=0, __expf(v)-1 ~1e-7 abs err — invisible vs 0.0625 floor (R11-validated)
__device__ __forceinline__ float elu1(float v) {
  return v > 0.0f ? v : (__expf(v) - 1.0f);
}

// single-plane fp16 activations (R7-validated: absmax 0.0625 vs 0.3625 threshold)
__device__ __forceinline__ short f2h(float v) {
  _Float16 h = (_Float16)v;
  return (short)__builtin_bit_cast(unsigned short, h);
}
__device__ __forceinline__ float h2f(unsigned short s) {
  return (float)__builtin_bit_cast(_Float16, s);
}
__device__ __forceinline__ unsigned packh2(float a, float b) {
  h2v p; p.x = (_Float16)a; p.y = (_Float16)b;
  return __builtin_bit_cast(unsigned, p);
}

// A-plane LDS addressing (R8/R11-validated): phys_unit = (2*oct+half+row)&31
__device__ __forceinline__ int a_addr(int row, int col, int half) {
  const int u = (2 * (col >> 3) + half + row) & 31;
  return row * ASTRIDE + u * 8 + (col & 7);
}

// ---------------- fused pre-pass (R15): Wmsg + W2 in ONE launch -------------
// blocks 0..511:   fp16 Wmsg, frag-linear order (512 KB at ws offset 0)
//   u32 layout: [l(8)][ks(8)][kind(2: T,B)][nt(4)][lane(64)][j2(4)]
//   value pair: k = ks*16 + (lane>>5)*8 + 2*j2 ; n = nt*32 + (lane&31)
// blocks 512..927: W2 -> 16x16x32 B-fragment order (416 KB at offset 131072 u32)
//   u32 layout: [n(13)][kt(4)][nt(8)][lane(64)][j2(4)]
//   value pair: k = kt*32 + (lane>>4)*8 + 2*j2 ; c = nt*16 + (lane&15)
__global__ void prep_all(const float* __restrict__ Wm,
                         const float* __restrict__ W2,
                         unsigned* __restrict__ ws) {
  if (blockIdx.x < 512) {
    int i = blockIdx.x * 256 + threadIdx.x;    // 0 .. 131071
    int j2   = i & 3;
    int lane = (i >> 2) & 63;
    int nt   = (i >> 8) & 3;
    int kind = (i >> 10) & 1;
    int ks   = (i >> 11) & 7;
    int l    = i >> 14;                        // 0..7
    int k = ks * 16 + ((lane >> 5) * 8) + 2 * j2;
    int n = nt * 32 + (lane & 31);
    int rbase = kind ? 128 : 0;                // bottom half of Wmsg rows = agg part
    float v0 = Wm[((l * 256) + rbase + k) * HH + n];
    float v1 = Wm[((l * 256) + rbase + k + 1) * HH + n];
    ws[i] = packh2(v0, v1);
  } else {
    int i = (blockIdx.x - 512) * 256 + threadIdx.x;  // 0 .. 106495
    int j2   = i & 3;
    int lane = (i >> 2) & 63;
    int nt   = (i >> 8) & 7;
    int kt   = (i >> 11) & 3;
    int n    = i >> 13;                        // 0..12
    int k = kt * 32 + (lane >> 4) * 8 + 2 * j2;
    int c = nt * 16 + (lane & 15);
    float v0 = W2[(n * HH + k) * HH + c];
    float v1 = W2[(n * HH + k + 1) * HH + c];
    ws[131072 + i] = packh2(v0, v1);
  }
}

// ---------------- main fused kernel (1024 thr, ONE block/CU, 1 tile/wave) ---
// R15 = R13 revert (best verified: 427us headline, 402-412 steady) + fused prep.
// R14's in-register N*Y_bot MFMA epilogue REVERTED: it cut VALUBusy 5pts but
// added serial MFMA latency to the per-layer critical path (wall +15us) —
// kernel at ~405us is latency-bound, not VALU-issue-bound.
// Phase 2 = per-node 16x16x32 MFMA (R13-validated); staging depth-2 prefetch
// (R12); single-plane fp16 activations (R7); epilogue SRCV gather (R7-R13).
__global__ __launch_bounds__(NTHR, 4)
void gnn_fused(const float* __restrict__ obs,
               const float* __restrict__ W1, const float* __restrict__ b1,
               const float* __restrict__ W2, const float* __restrict__ b2,
               const float* __restrict__ bm,
               const float* __restrict__ Wo, const float* __restrict__ bo,
               const float* __restrict__ wmsw,   // d_ws: [Wmsg fp16 512KB][W2 frags 416KB]
               float* __restrict__ out)
{
  // A-planes: x state fp16 hi, 128 rows (elem*16+node), swizzled 16B units
  __shared__ short As[128 * ASTRIDE];      // 65536 B ; aliased as fp16 hb scratch
  __shared__ float Bb[2][4096];            // 2 x 16 KB (ks-PAIR fp16) ping-pong -> 98304 B

  const int t    = threadIdx.x;
  const int wid  = t >> 6;        // wave 0..15
  const int mq   = wid >> 2;      // m-tile 0..3: rows mq*32 .. mq*32+31
  const int nq   = wid & 3;       // n-quarter 0..3: cols nq*32 .. nq*32+31
  const int lane = t & 63;
  const int l31  = lane & 31;
  const int lh   = lane >> 5;     // k-half within frag / row-group bit in C
  const bool h1  = (lh == 1);
  const int g    = t >> 5;        // 32-thread group 0..31 (VALU phases)
  const int og   = t & 31;
  const int o0   = og << 2;
  const int b0   = blockIdx.x * TB;

  const F4* wsrc4 = (const F4*)wmsw;
  short* hb = As;                 // h scratch: [n(13)][row(16, 8 used)][HBS shorts]
                                  // 13*16*136 = 28288 shorts = 56576 B < 65536 B
  F4* bufA = (F4*)Bb;             // 1024 F4 each
  F4* bufB = ((F4*)Bb) + 1024;
  float* xnb = Bb[1];             // xn gather scratch (3744 floats < 4096)
  const unsigned* w2fb = ((const unsigned*)wmsw) + 131072;  // W2 fragment base

  // ---------- Phase 0: gather xn ----------
  for (int i = t; i < TB * NN * DMAX; i += NTHR) {
    int d  = i % DMAX;
    int r  = i / DMAX;
    int nn = r % NN;
    int bb = r / NN;
    int fi = c_feat[nn * DMAX + d];
    float v = (fi >= 0) ? obs[(b0 + bb) * OBSD + fi] : 0.0f;
    xnb[(bb * NN + nn) * 36 + d] = v;
  }
  __syncthreads();

  // ---------- Phase 1 (VALU): h = elu(xn @ W1 + b1) -> hb fp16 rows ---------
  {
    const int n  = g >> 1;         // 0..15, active < 13
    const int q0 = (g & 1) * 4;    // 4 elems per group
    if (n < NN) {
      float acc[4][4];
      const F4 bv = *(const F4*)(b1 + n * HH + o0);
      #pragma unroll
      for (int q = 0; q < 4; ++q) { acc[q][0]=bv.x; acc[q][1]=bv.y; acc[q][2]=bv.z; acc[q][3]=bv.w; }
      #pragma unroll 3
      for (int k = 0; k < DMAX; ++k) {
        const F4 w = *(const F4*)(W1 + (n * DMAX + k) * HH + o0);
        #pragma unroll
        for (int q = 0; q < 4; ++q) {
          const float xv = xnb[((q0 + q) * NN + n) * 36 + k];
          acc[q][0] += xv * w.x; acc[q][1] += xv * w.y;
          acc[q][2] += xv * w.z; acc[q][3] += xv * w.w;
        }
      }
      #pragma unroll
      for (int q = 0; q < 4; ++q) {
        short4 hv;
        hv.x = f2h(elu1(acc[q][0])); hv.y = f2h(elu1(acc[q][1]));
        hv.z = f2h(elu1(acc[q][2])); hv.w = f2h(elu1(acc[q][3]));
        *(short4*)(hb + (n * 16 + (q0 + q)) * HBS + o0) = hv;
      }
    }
  }
  __syncthreads();

  // ---------- Phase 2 (MFMA): x = h @ W2 + b2, per-node 16x16x32 ------------
  f32x4 acc2[8];
  {
    if (wid < NN) {
      const int n    = wid;
      const int arow = lane & 15;
      const int kof  = (lane >> 4) * 8;
      h8v af[4];
      #pragma unroll
      for (int kt = 0; kt < 4; ++kt)
        af[kt] = *(const h8v*)(hb + (n * 16 + arow) * HBS + kt * 32 + kof);
      const uint4* wf = (const uint4*)w2fb;
      #pragma unroll
      for (int nt = 0; nt < 8; ++nt) {
        const float bias = b2[n * HH + nt * 16 + (lane & 15)];
        acc2[nt][0] = bias; acc2[nt][1] = bias;
        acc2[nt][2] = bias; acc2[nt][3] = bias;
        #pragma unroll
        for (int kt = 0; kt < 4; ++kt) {
          const uint4 wv = wf[((n * 4 + kt) * 8 + nt) * 64 + lane];
          acc2[nt] = __builtin_amdgcn_mfma_f32_16x16x32_f16(
                       af[kt], __builtin_bit_cast(h8v, wv), acc2[nt], 0, 0, 0);
        }
      }
    }
  }
  __syncthreads();   // all hb reads done; safe to overwrite As with x planes
  {
    // re-zero pad rows (hb clobbered Phase-0-style zeros); whole rows, swizzle-safe
    for (int i = t; i < 24 * HSTRIDE; i += NTHR) {
      int pr = i / HSTRIDE, off = i % HSTRIDE;
      int row = (pr / 3) * 16 + 13 + (pr % 3);
      ((int*)As)[row * HSTRIDE + off] = 0;
    }
    if (wid < NN) {
      const int n  = wid;
      const int e0 = (lane >> 4) * 4;     // C row base: 0,4,8,12
      if (e0 < 8) {
        #pragma unroll
        for (int nt = 0; nt < 8; ++nt) {
          const int col = nt * 16 + (lane & 15);
          #pragma unroll
          for (int rg = 0; rg < 4; ++rg) {
            const int row = (e0 + rg) * 16 + n;
            As[a_addr(row, col, 0)] = f2h(acc2[nt][rg]);
          }
        }
      }
    }
  }
  __syncthreads();

  // ---------- Phase 3: 8 MFMA layers (fp16 single-plane, depth-2 prefetch) --
  {
    // prologue: stage pair 0 to LDS; prefetch pair 1 into regs
    bufA[t] = wsrc4[t];
    F4 rnext = wsrc4[1024 + t];
    __syncthreads();

    #pragma unroll 1
    for (int l = 0; l < NL; ++l) {
      f32x16 aT, aB;
      #pragma unroll
      for (int r = 0; r < 16; ++r) { aT[r] = 0.f; aB[r] = 0.f; }

      #pragma unroll 1
      for (int kp = 0; kp < 4; ++kp) {
        const int gpc = l * 4 + kp;          // global pair index 0..31
        F4* cur = (gpc & 1) ? bufB : bufA;
        F4* nxt = (gpc & 1) ? bufA : bufB;

        F4 rnext2;
        const bool more2 = (gpc + 2 < NL * 4);
        if (more2) rnext2 = wsrc4[(size_t)(gpc + 2) * 1024 + t];

        #pragma unroll
        for (int kk = 0; kk < 2; ++kk) {
          const int ks = kp * 2 + kk;
          // 8 KB sub-chunk = 4096 shorts
          const short* bb = ((const short*)cur) + kk * 4096;

          h8v ah;
          {
            const int row = mq * 32 + l31;
            const int p = 2 * ks + lh;         // oct index 0..15
            ah = *(const h8v*)(As + row * ASTRIDE + (((2 * p + row) & 31) * 8));
          }
          const h8v bth = *(const h8v*)(bb + ((0 * 4 + nq) * 64 + lane) * 8);
          const h8v bbh = *(const h8v*)(bb + ((1 * 4 + nq) * 64 + lane) * 8);

          aT = __builtin_amdgcn_mfma_f32_32x32x16_f16(ah, bth, aT, 0, 0, 0);
          aB = __builtin_amdgcn_mfma_f32_32x32x16_f16(ah, bbh, aB, 0, 0, 0);
        }

        if (gpc + 1 < NL * 4) nxt[t] = rnext;  // write pair gpc+1 (loaded last window)
        __syncthreads();   // publishes nxt; guards cur reuse and A-row overwrite
        rnext = rnext2;
      }

      // epilogue: x_new = elu(Y_top + N*Y_bot + bias) ; fp16 store to As
      {
        const int col  = nq * 32 + l31;
        const float bias = bm[l * HH + col];
        float cb[16], sw[16];
        #pragma unroll
        for (int r = 0; r < 16; ++r) { cb[r] = aB[r]; sw[r] = __shfl_xor(cb[r], 32); }

        #pragma unroll
        for (int r = 0; r < 16; ++r) {
          const int p  = (r & 3) + 8 * (r >> 2);
          const int n0 = p & 15;            // node for lane-half 0 (always < 13)
          const int n1 = n0 + 4;            // node for lane-half 1 (may be pad)
          const int es = p >> 4;
          #define SRCV(np)                                                \
            ({ const int rl = (es << 4) + (np);                           \
               const int hp = (rl >> 2) & 1;                              \
               const int pp = rl - 4 * hp;                                \
               const int rp = (pp & 3) + 4 * (pp >> 3);                   \
               (hp == 1) ? (h1 ? cb[rp] : sw[rp])                         \
                         : (h1 ? sw[rp] : cb[rp]); })
          float a0 = SRCV(ADJ[n0][0]);
          if (DEG[n0] > 1) a0 += SRCV(ADJ[n0][1]);
          if (DEG[n0] > 2) a0 += SRCV(ADJ[n0][2]);
          float a1 = 0.f;
          if (n1 < NN) {
            a1 = SRCV(ADJ[n1][0]);
            if (DEG[n1] > 1) a1 += SRCV(ADJ[n1][1]);
            if (DEG[n1] > 2) a1 += SRCV(ADJ[n1][2]);
          }
          #undef SRCV
          const float agg = h1 ? a1 : a0;
          const float tot = aT[r] + agg + bias;
          float xv = elu1(tot);
          if (n1 >= NN) xv = h1 ? 0.f : xv;     // pad rows stay zero (stored)
          const int row = mq * 32 + p + 4 * lh;
          As[a_addr(row, col, 0)] = f2h(xv);
        }
      }
      __syncthreads();
    }
  }

  // ---------- Phase 4: readout ----------------------------------------------
  if (g < TB) {
    const int elem = g;          // 0..7
    const int c = og * 4;        // 4 channels per thread
    float xv[NN][4];
    #pragma unroll
    for (int n = 0; n < NN; ++n) {
      const int row = elem * 16 + n;
      const ushort4 uh = *(const ushort4*)(As + a_addr(row, c, 0));
      xv[n][0] = h2f(uh.x);
      xv[n][1] = h2f(uh.y);
      xv[n][2] = h2f(uh.z);
      xv[n][3] = h2f(uh.w);
    }
    #pragma unroll
    for (int j = 0; j < NJ; ++j) {
      const F4 wa = *(const F4*)(Wo + j * 256 + c);
      const F4 wb = *(const F4*)(Wo + j * 256 + 128 + c);
      const float* xa = xv[JM0[j]];
      const float* xb = xv[JM1[j]];
      float p = xa[0]*wa.x + xa[1]*wa.y + xa[2]*wa.z + xa[3]*wa.w
              + xb[0]*wb.x + xb[1]*wb.y + xb[2]*wb.z + xb[3]*wb.w;
      p += __shfl_xor(p, 16);
      p += __shfl_xor(p, 8);
      p += __shfl_xor(p, 4);
      p += __shfl_xor(p, 2);
      p += __shfl_xor(p, 1);
      if (og == 0) out[(b0 + elem) * NJ + j] = p + bo[j];
    }
  }
}

extern "C" void kernel_launch(void* const* d_in, const int* in_sizes, int n_in,
                              void* d_out, int out_size, void* d_ws, size_t ws_size,
                              hipStream_t stream) {
  const float* obs = (const float*)d_in[0];
  const float* W1  = (const float*)d_in[1];
  const float* b1  = (const float*)d_in[2];
  const float* W2  = (const float*)d_in[3];
  const float* b2  = (const float*)d_in[4];
  const float* Wm  = (const float*)d_in[5];
  const float* bm  = (const float*)d_in[6];
  const float* Wo  = (const float*)d_in[7];
  const float* bo  = (const float*)d_in[8];
  float* out = (float*)d_out;

  const int B = in_sizes[0] / OBSD;   // 16384
  const int nblk = B / TB;            // 2048

  // fused pre-pass: fp16 Wmsg (512 KB) + W2 16x16x32 B-fragments (416 KB)
  prep_all<<<928, 256, 0, stream>>>(Wm, W2, (unsigned*)d_ws);
  gnn_fused<<<nblk, NTHR, 0, stream>>>(obs, W1, b1, W2, b2, bm, Wo, bo,
                                       (const float*)d_ws, out);
}

// Round 16
// 424.932 us; speedup vs baseline: 1.0311x; 1.0311x over previous
//
#include <hip/hip_runtime.h>
#include <math.h>

#define NN   13
#define HH   128
#define NL   8
#define NJ   17
#define OBSD 348
#define DMAX 33
#define TB   8
#define NTHR 1024
#define ASTRIDE 256   // shorts per A row = 512 B; unit-swizzled (R8/R11-validated)
#define HSTRIDE 128   // same row viewed as fp32
#define HBS  136      // hb row stride in shorts (272 B; bank-spread, 16B-aligned)
#define XNS  72       // xn16 row stride in shorts (144 B; bank-spread, 16B-aligned)

// FEAT_IDX table (13 x 33), pad = -1
__constant__ int c_feat[NN * DMAX] = {
  0,1,2,3,4,22,23,24,25,26,27,45,46,47,48,49,50,51,52,53,54,175,176,177,178,179,180,270,271,272,273,274,275,
  5,6,28,29,55,56,57,58,59,60,61,62,63,64,181,182,183,184,185,186,276,277,278,279,280,281,-1,-1,-1,-1,-1,-1,-1,
  7,30,65,66,67,68,69,70,71,72,73,74,187,188,189,190,191,192,253,254,255,282,283,284,285,286,287,-1,-1,-1,-1,-1,-1,
  8,9,10,11,31,32,33,34,75,76,77,78,79,80,81,82,83,84,193,194,195,196,197,198,256,257,258,288,289,290,291,292,293,
  11,34,85,86,87,88,89,90,91,92,93,94,199,200,201,202,203,204,259,294,295,296,297,298,299,-1,-1,-1,-1,-1,-1,-1,-1,
  95,96,97,98,99,100,101,102,103,104,205,206,207,208,209,210,300,301,302,303,304,305,-1,-1,-1,-1,-1,-1,-1,-1,-1,-1,-1,
  12,13,14,15,35,36,37,38,105,106,107,108,109,110,111,112,113,114,211,212,213,214,215,216,260,261,262,306,307,308,309,310,311,
  15,38,115,116,117,118,119,120,121,122,123,124,217,218,219,220,221,222,263,312,313,314,315,316,317,-1,-1,-1,-1,-1,-1,-1,-1,
  125,126,127,128,129,130,131,132,133,134,223,224,225,226,227,228,318,319,320,321,322,323,-1,-1,-1,-1,-1,-1,-1,-1,-1,-1,-1,
  16,17,18,39,40,41,135,136,137,138,139,140,141,142,143,144,229,230,231,232,233,234,264,265,324,325,326,327,328,329,-1,-1,-1,
  18,41,145,146,147,148,149,150,151,152,153,154,235,236,237,238,239,240,266,330,331,332,333,334,335,-1,-1,-1,-1,-1,-1,-1,-1,
  19,20,21,42,43,44,155,156,157,158,159,160,161,162,163,164,241,242,243,244,245,246,267,268,336,337,338,339,340,341,-1,-1,-1,
  21,44,165,166,167,168,169,170,171,172,173,174,247,248,249,250,251,252,269,342,343,344,345,346,347,-1,-1,-1,-1,-1,-1,-1,-1
};

__device__ constexpr int ADJ[NN][3] = {
  {1,9,11},{0,2,0},{1,3,6},{2,4,0},{3,5,0},{4,0,0},{2,7,0},
  {6,8,0},{7,0,0},{0,10,0},{9,0,0},{0,12,0},{11,0,0}
};
__device__ constexpr int DEG[NN] = {3,2,3,2,2,1,2,2,1,2,1,2,1};
__device__ constexpr int JM0[NJ] = {1,1,1,2,2,2,3,2,2,2,6,0,0,9,0,0,11};
__device__ constexpr int JM1[NJ] = {2,2,2,3,3,3,4,6,6,6,7,9,9,10,11,11,12};

typedef float4 F4;
using h8v = __attribute__((ext_vector_type(8))) _Float16;  // 8 fp16 (4 VGPR)
using h2v = __attribute__((ext_vector_type(2))) _Float16;  // packed half2
using f32x4  = __attribute__((ext_vector_type(4)))  float; // MFMA 16x16 C/D
using f32x16 = __attribute__((ext_vector_type(16))) float; // MFMA 32x32 C/D

// elu: for v<=0, __expf(v)-1 ~1e-7 abs err — invisible vs 0.0625 floor (R11-validated)
__device__ __forceinline__ float elu1(float v) {
  return v > 0.0f ? v : (__expf(v) - 1.0f);
}

// single-plane fp16 activations (R7-validated: absmax 0.0625 vs 0.3625 threshold)
__device__ __forceinline__ short f2h(float v) {
  _Float16 h = (_Float16)v;
  return (short)__builtin_bit_cast(unsigned short, h);
}
__device__ __forceinline__ float h2f(unsigned short s) {
  return (float)__builtin_bit_cast(_Float16, s);
}
__device__ __forceinline__ unsigned packh2(float a, float b) {
  h2v p; p.x = (_Float16)a; p.y = (_Float16)b;
  return __builtin_bit_cast(unsigned, p);
}

// A-plane LDS addressing (R8/R11-validated): phys_unit = (2*oct+half+row)&31
__device__ __forceinline__ int a_addr(int row, int col, int half) {
  const int u = (2 * (col >> 3) + half + row) & 31;
  return row * ASTRIDE + u * 8 + (col & 7);
}

// ---------------- fused pre-pass: Wmsg + W2 + (optional) W1 in ONE launch ---
// blocks 0..511:    fp16 Wmsg, frag-linear order (512 KB at ws offset 0)
// blocks 512..927:  W2 -> 16x16x32 B-fragments (416 KB at offset 131072 u32)
// blocks 928..1135: W1 -> 16x16x32 B-fragments, K padded 33->64 with zeros
//                   (208 KB at offset 237568 u32) — launched only if ws fits.
__global__ void prep_all(const float* __restrict__ Wm,
                         const float* __restrict__ W2,
                         const float* __restrict__ W1,
                         unsigned* __restrict__ ws) {
  if (blockIdx.x < 512) {
    int i = blockIdx.x * 256 + threadIdx.x;    // 0 .. 131071
    int j2   = i & 3;
    int lane = (i >> 2) & 63;
    int nt   = (i >> 8) & 3;
    int kind = (i >> 10) & 1;
    int ks   = (i >> 11) & 7;
    int l    = i >> 14;                        // 0..7
    int k = ks * 16 + ((lane >> 5) * 8) + 2 * j2;
    int n = nt * 32 + (lane & 31);
    int rbase = kind ? 128 : 0;                // bottom half of Wmsg rows = agg part
    float v0 = Wm[((l * 256) + rbase + k) * HH + n];
    float v1 = Wm[((l * 256) + rbase + k + 1) * HH + n];
    ws[i] = packh2(v0, v1);
  } else if (blockIdx.x < 928) {
    int i = (blockIdx.x - 512) * 256 + threadIdx.x;  // 0 .. 106495
    int j2   = i & 3;
    int lane = (i >> 2) & 63;
    int nt   = (i >> 8) & 7;
    int kt   = (i >> 11) & 3;
    int n    = i >> 13;                        // 0..12
    int k = kt * 32 + (lane >> 4) * 8 + 2 * j2;
    int c = nt * 16 + (lane & 15);
    float v0 = W2[(n * HH + k) * HH + c];
    float v1 = W2[(n * HH + k + 1) * HH + c];
    ws[131072 + i] = packh2(v0, v1);
  } else {
    int i = (blockIdx.x - 928) * 256 + threadIdx.x;  // 0 .. 53247
    int j2   = i & 3;
    int lane = (i >> 2) & 63;
    int nt   = (i >> 8) & 7;
    int kt   = (i >> 11) & 1;
    int n    = i >> 12;                        // 0..12
    int k = kt * 32 + (lane >> 4) * 8 + 2 * j2;
    int c = nt * 16 + (lane & 15);
    float v0 = (k     < DMAX) ? W1[(n * DMAX + k) * HH + c]     : 0.f;
    float v1 = (k + 1 < DMAX) ? W1[(n * DMAX + k + 1) * HH + c] : 0.f;
    ws[237568 + i] = packh2(v0, v1);
  }
}

// ---------------- main fused kernel (1024 thr, ONE block/CU, 1 tile/wave) ---
// R16-change vs R15/R13 (402-412us steady): Phase 1 moved onto the matrix
// pipe (same per-node 16x16x32 mapping R13 validated for Phase 2; K padded
// 33->64). Phase 0 gathers xn directly as fp16 (stride XNS=72, bank-spread)
// into Bb. Runtime-guarded: w1go=0 -> VALU fallback (old Phase 1, fp16 xn).
// Phase 2/3/4, staging (depth-2), epilogue byte-identical to R13/R15.
__global__ __launch_bounds__(NTHR, 4)
void gnn_fused(const float* __restrict__ obs,
               const float* __restrict__ W1, const float* __restrict__ b1,
               const float* __restrict__ W2, const float* __restrict__ b2,
               const float* __restrict__ bm,
               const float* __restrict__ Wo, const float* __restrict__ bo,
               const float* __restrict__ wmsw,   // d_ws: [Wmsg 512K][W2 416K][W1 208K]
               float* __restrict__ out, int w1go)
{
  // A-planes: x state fp16 hi, 128 rows (elem*16+node), swizzled 16B units
  __shared__ short As[128 * ASTRIDE];      // 65536 B ; aliased as fp16 hb scratch
  __shared__ float Bb[2][4096];            // 2 x 16 KB (ks-PAIR fp16) ping-pong -> 98304 B

  const int t    = threadIdx.x;
  const int wid  = t >> 6;        // wave 0..15
  const int mq   = wid >> 2;      // m-tile 0..3: rows mq*32 .. mq*32+31
  const int nq   = wid & 3;       // n-quarter 0..3: cols nq*32 .. nq*32+31
  const int lane = t & 63;
  const int l31  = lane & 31;
  const int lh   = lane >> 5;     // k-half within frag / row-group bit in C
  const bool h1  = (lh == 1);
  const int g    = t >> 5;        // 32-thread group 0..31 (VALU phases)
  const int og   = t & 31;
  const int o0   = og << 2;
  const int b0   = blockIdx.x * TB;

  const F4* wsrc4 = (const F4*)wmsw;
  short* hb = As;                 // h scratch: [n(13)][row(16, 8 used)][HBS shorts]
  short* xn16 = (short*)Bb;       // xn fp16: [n(13)][row(16, 8 used)][XNS shorts]
                                  // 13*16*72 = 14976 shorts = 29952 B < 32768 B
  F4* bufA = (F4*)Bb;             // 1024 F4 each
  F4* bufB = ((F4*)Bb) + 1024;
  const unsigned* w2fb = ((const unsigned*)wmsw) + 131072;  // W2 fragment base
  const unsigned* w1fb = ((const unsigned*)wmsw) + 237568;  // W1 fragment base

  // ---------- Phase 0: gather xn as fp16, K padded to 64 ----------
  for (int i = t; i < TB * NN * 64; i += NTHR) {
    int d  = i & 63;
    int r  = i >> 6;
    int nn = r % NN;
    int bb = r / NN;
    int fi = (d < DMAX) ? c_feat[nn * DMAX + d] : -1;
    float v = (fi >= 0) ? obs[(b0 + bb) * OBSD + fi] : 0.0f;
    xn16[(nn * 16 + bb) * XNS + d] = f2h(v);
  }
  __syncthreads();

  // ---------- Phase 1: h = elu(xn @ W1 + b1) -> hb fp16 rows ----------------
  if (w1go) {
    // MFMA path: wave = node, 16x16x32, K=64 (2 k-tiles), 8 n-tiles.
    // A rows 8..15 are garbage (unwritten xn16) -> C rows 8..15 discarded.
    if (wid < NN) {
      const int n    = wid;
      const int arow = lane & 15;
      const int kof  = (lane >> 4) * 8;
      const h8v af0 = *(const h8v*)(xn16 + (n * 16 + arow) * XNS + 0 + kof);
      const h8v af1 = *(const h8v*)(xn16 + (n * 16 + arow) * XNS + 32 + kof);
      const uint4* wf = (const uint4*)w1fb;
      const int re = (lane >> 4) * 4;     // C row base: 0,4,8,12
      #pragma unroll
      for (int nt = 0; nt < 8; ++nt) {
        f32x4 a;
        const float bias = b1[n * HH + nt * 16 + (lane & 15)];
        a[0] = bias; a[1] = bias; a[2] = bias; a[3] = bias;
        const uint4 wv0 = wf[((n * 2 + 0) * 8 + nt) * 64 + lane];
        const uint4 wv1 = wf[((n * 2 + 1) * 8 + nt) * 64 + lane];
        a = __builtin_amdgcn_mfma_f32_16x16x32_f16(af0, __builtin_bit_cast(h8v, wv0), a, 0, 0, 0);
        a = __builtin_amdgcn_mfma_f32_16x16x32_f16(af1, __builtin_bit_cast(h8v, wv1), a, 0, 0, 0);
        if (re < 8) {
          #pragma unroll
          for (int rg = 0; rg < 4; ++rg)
            hb[(n * 16 + re + rg) * HBS + nt * 16 + (lane & 15)] = f2h(elu1(a[rg]));
        }
      }
    }
  } else {
    // VALU fallback (old Phase 1, reads fp16 xn)
    const int n  = g >> 1;         // 0..15, active < 13
    const int q0 = (g & 1) * 4;    // 4 elems per group
    if (n < NN) {
      float acc[4][4];
      const F4 bv = *(const F4*)(b1 + n * HH + o0);
      #pragma unroll
      for (int q = 0; q < 4; ++q) { acc[q][0]=bv.x; acc[q][1]=bv.y; acc[q][2]=bv.z; acc[q][3]=bv.w; }
      #pragma unroll 3
      for (int k = 0; k < DMAX; ++k) {
        const F4 w = *(const F4*)(W1 + (n * DMAX + k) * HH + o0);
        #pragma unroll
        for (int q = 0; q < 4; ++q) {
          const float xv = h2f((unsigned short)xn16[(n * 16 + q0 + q) * XNS + k]);
          acc[q][0] += xv * w.x; acc[q][1] += xv * w.y;
          acc[q][2] += xv * w.z; acc[q][3] += xv * w.w;
        }
      }
      #pragma unroll
      for (int q = 0; q < 4; ++q) {
        short4 hv;
        hv.x = f2h(elu1(acc[q][0])); hv.y = f2h(elu1(acc[q][1]));
        hv.z = f2h(elu1(acc[q][2])); hv.w = f2h(elu1(acc[q][3]));
        *(short4*)(hb + (n * 16 + (q0 + q)) * HBS + o0) = hv;
      }
    }
  }
  __syncthreads();

  // ---------- Phase 2 (MFMA): x = h @ W2 + b2, per-node 16x16x32 ------------
  f32x4 acc2[8];
  {
    if (wid < NN) {
      const int n    = wid;
      const int arow = lane & 15;
      const int kof  = (lane >> 4) * 8;
      h8v af[4];
      #pragma unroll
      for (int kt = 0; kt < 4; ++kt)
        af[kt] = *(const h8v*)(hb + (n * 16 + arow) * HBS + kt * 32 + kof);
      const uint4* wf = (const uint4*)w2fb;
      #pragma unroll
      for (int nt = 0; nt < 8; ++nt) {
        const float bias = b2[n * HH + nt * 16 + (lane & 15)];
        acc2[nt][0] = bias; acc2[nt][1] = bias;
        acc2[nt][2] = bias; acc2[nt][3] = bias;
        #pragma unroll
        for (int kt = 0; kt < 4; ++kt) {
          const uint4 wv = wf[((n * 4 + kt) * 8 + nt) * 64 + lane];
          acc2[nt] = __builtin_amdgcn_mfma_f32_16x16x32_f16(
                       af[kt], __builtin_bit_cast(h8v, wv), acc2[nt], 0, 0, 0);
        }
      }
    }
  }
  __syncthreads();   // all hb reads done; safe to overwrite As with x planes
  {
    // re-zero pad rows (hb clobbered them); whole rows, swizzle-safe
    for (int i = t; i < 24 * HSTRIDE; i += NTHR) {
      int pr = i / HSTRIDE, off = i % HSTRIDE;
      int row = (pr / 3) * 16 + 13 + (pr % 3);
      ((int*)As)[row * HSTRIDE + off] = 0;
    }
    if (wid < NN) {
      const int n  = wid;
      const int e0 = (lane >> 4) * 4;     // C row base: 0,4,8,12
      if (e0 < 8) {
        #pragma unroll
        for (int nt = 0; nt < 8; ++nt) {
          const int col = nt * 16 + (lane & 15);
          #pragma unroll
          for (int rg = 0; rg < 4; ++rg) {
            const int row = (e0 + rg) * 16 + n;
            As[a_addr(row, col, 0)] = f2h(acc2[nt][rg]);
          }
        }
      }
    }
  }
  __syncthreads();

  // ---------- Phase 3: 8 MFMA layers (fp16 single-plane, depth-2 prefetch) --
  {
    // prologue: stage pair 0 to LDS; prefetch pair 1 into regs
    bufA[t] = wsrc4[t];
    F4 rnext = wsrc4[1024 + t];
    __syncthreads();

    #pragma unroll 1
    for (int l = 0; l < NL; ++l) {
      f32x16 aT, aB;
      #pragma unroll
      for (int r = 0; r < 16; ++r) { aT[r] = 0.f; aB[r] = 0.f; }

      #pragma unroll 1
      for (int kp = 0; kp < 4; ++kp) {
        const int gpc = l * 4 + kp;          // global pair index 0..31
        F4* cur = (gpc & 1) ? bufB : bufA;
        F4* nxt = (gpc & 1) ? bufA : bufB;

        F4 rnext2;
        const bool more2 = (gpc + 2 < NL * 4);
        if (more2) rnext2 = wsrc4[(size_t)(gpc + 2) * 1024 + t];

        #pragma unroll
        for (int kk = 0; kk < 2; ++kk) {
          const int ks = kp * 2 + kk;
          // 8 KB sub-chunk = 4096 shorts
          const short* bb = ((const short*)cur) + kk * 4096;

          h8v ah;
          {
            const int row = mq * 32 + l31;
            const int p = 2 * ks + lh;         // oct index 0..15
            ah = *(const h8v*)(As + row * ASTRIDE + (((2 * p + row) & 31) * 8));
          }
          const h8v bth = *(const h8v*)(bb + ((0 * 4 + nq) * 64 + lane) * 8);
          const h8v bbh = *(const h8v*)(bb + ((1 * 4 + nq) * 64 + lane) * 8);

          aT = __builtin_amdgcn_mfma_f32_32x32x16_f16(ah, bth, aT, 0, 0, 0);
          aB = __builtin_amdgcn_mfma_f32_32x32x16_f16(ah, bbh, aB, 0, 0, 0);
        }

        if (gpc + 1 < NL * 4) nxt[t] = rnext;  // write pair gpc+1 (loaded last window)
        __syncthreads();   // publishes nxt; guards cur reuse and A-row overwrite
        rnext = rnext2;
      }

      // epilogue: x_new = elu(Y_top + N*Y_bot + bias) ; fp16 store to As
      {
        const int col  = nq * 32 + l31;
        const float bias = bm[l * HH + col];
        float cb[16], sw[16];
        #pragma unroll
        for (int r = 0; r < 16; ++r) { cb[r] = aB[r]; sw[r] = __shfl_xor(cb[r], 32); }

        #pragma unroll
        for (int r = 0; r < 16; ++r) {
          const int p  = (r & 3) + 8 * (r >> 2);
          const int n0 = p & 15;            // node for lane-half 0 (always < 13)
          const int n1 = n0 + 4;            // node for lane-half 1 (may be pad)
          const int es = p >> 4;
          #define SRCV(np)                                                \
            ({ const int rl = (es << 4) + (np);                           \
               const int hp = (rl >> 2) & 1;                              \
               const int pp = rl - 4 * hp;                                \
               const int rp = (pp & 3) + 4 * (pp >> 3);                   \
               (hp == 1) ? (h1 ? cb[rp] : sw[rp])                         \
                         : (h1 ? sw[rp] : cb[rp]); })
          float a0 = SRCV(ADJ[n0][0]);
          if (DEG[n0] > 1) a0 += SRCV(ADJ[n0][1]);
          if (DEG[n0] > 2) a0 += SRCV(ADJ[n0][2]);
          float a1 = 0.f;
          if (n1 < NN) {
            a1 = SRCV(ADJ[n1][0]);
            if (DEG[n1] > 1) a1 += SRCV(ADJ[n1][1]);
            if (DEG[n1] > 2) a1 += SRCV(ADJ[n1][2]);
          }
          #undef SRCV
          const float agg = h1 ? a1 : a0;
          const float tot = aT[r] + agg + bias;
          float xv = elu1(tot);
          if (n1 >= NN) xv = h1 ? 0.f : xv;     // pad rows stay zero (stored)
          const int row = mq * 32 + p + 4 * lh;
          As[a_addr(row, col, 0)] = f2h(xv);
        }
      }
      __syncthreads();
    }
  }

  // ---------- Phase 4: readout ----------------------------------------------
  if (g < TB) {
    const int elem = g;          // 0..7
    const int c = og * 4;        // 4 channels per thread
    float xv[NN][4];
    #pragma unroll
    for (int n = 0; n < NN; ++n) {
      const int row = elem * 16 + n;
      const ushort4 uh = *(const ushort4*)(As + a_addr(row, c, 0));
      xv[n][0] = h2f(uh.x);
      xv[n][1] = h2f(uh.y);
      xv[n][2] = h2f(uh.z);
      xv[n][3] = h2f(uh.w);
    }
    #pragma unroll
    for (int j = 0; j < NJ; ++j) {
      const F4 wa = *(const F4*)(Wo + j * 256 + c);
      const F4 wb = *(const F4*)(Wo + j * 256 + 128 + c);
      const float* xa = xv[JM0[j]];
      const float* xb = xv[JM1[j]];
      float p = xa[0]*wa.x + xa[1]*wa.y + xa[2]*wa.z + xa[3]*wa.w
              + xb[0]*wb.x + xb[1]*wb.y + xb[2]*wb.z + xb[3]*wb.w;
      p += __shfl_xor(p, 16);
      p += __shfl_xor(p, 8);
      p += __shfl_xor(p, 4);
      p += __shfl_xor(p, 2);
      p += __shfl_xor(p, 1);
      if (og == 0) out[(b0 + elem) * NJ + j] = p + bo[j];
    }
  }
}

extern "C" void kernel_launch(void* const* d_in, const int* in_sizes, int n_in,
                              void* d_out, int out_size, void* d_ws, size_t ws_size,
                              hipStream_t stream) {
  const float* obs = (const float*)d_in[0];
  const float* W1  = (const float*)d_in[1];
  const float* b1  = (const float*)d_in[2];
  const float* W2  = (const float*)d_in[3];
  const float* b2  = (const float*)d_in[4];
  const float* Wm  = (const float*)d_in[5];
  const float* bm  = (const float*)d_in[6];
  const float* Wo  = (const float*)d_in[7];
  const float* bo  = (const float*)d_in[8];
  float* out = (float*)d_out;

  const int B = in_sizes[0] / OBSD;   // 16384
  const int nblk = B / TB;            // 2048

  // ws need: Wmsg 131072 + W2 106496 + W1 53248 u32 = 1,163,264 B
  const size_t need = (size_t)(131072 + 106496 + 53248) * 4;
  const int w1go = (ws_size >= need) ? 1 : 0;

  // fused pre-pass (W1 fragment blocks launched only when they fit in ws)
  prep_all<<<w1go ? 1136 : 928, 256, 0, stream>>>(Wm, W2, W1, (unsigned*)d_ws);
  gnn_fused<<<nblk, NTHR, 0, stream>>>(obs, W1, b1, W2, b2, bm, Wo, bo,
                                       (const float*)d_ws, out, w1go);
}

// Round 17
// 351.380 us; speedup vs baseline: 1.2470x; 1.2093x over previous
//
#include <hip/hip_runtime.h>
#include <math.h>

#define NN   13
#define HH   128
#define NL   8
#define NJ   17
#define OBSD 348
#define DMAX 33
#define TB   16
#define NTHR 1024
#define ASTRIDE 256   // shorts per A row = 512 B; unit-swizzled (R8/R11-validated)
#define HSTRIDE 128   // same row viewed as fp32
#define HBS  136      // hb row stride in shorts (272 B; bank-spread, 16B-aligned)
#define XNS  72       // xn16 row stride in shorts (144 B; bank-spread, 16B-aligned)

// FEAT_IDX table (13 x 33), pad = -1
__constant__ int c_feat[NN * DMAX] = {
  0,1,2,3,4,22,23,24,25,26,27,45,46,47,48,49,50,51,52,53,54,175,176,177,178,179,180,270,271,272,273,274,275,
  5,6,28,29,55,56,57,58,59,60,61,62,63,64,181,182,183,184,185,186,276,277,278,279,280,281,-1,-1,-1,-1,-1,-1,-1,
  7,30,65,66,67,68,69,70,71,72,73,74,187,188,189,190,191,192,253,254,255,282,283,284,285,286,287,-1,-1,-1,-1,-1,-1,
  8,9,10,11,31,32,33,34,75,76,77,78,79,80,81,82,83,84,193,194,195,196,197,198,256,257,258,288,289,290,291,292,293,
  11,34,85,86,87,88,89,90,91,92,93,94,199,200,201,202,203,204,259,294,295,296,297,298,299,-1,-1,-1,-1,-1,-1,-1,-1,
  95,96,97,98,99,100,101,102,103,104,205,206,207,208,209,210,300,301,302,303,304,305,-1,-1,-1,-1,-1,-1,-1,-1,-1,-1,-1,
  12,13,14,15,35,36,37,38,105,106,107,108,109,110,111,112,113,114,211,212,213,214,215,216,260,261,262,306,307,308,309,310,311,
  15,38,115,116,117,118,119,120,121,122,123,124,217,218,219,220,221,222,263,312,313,314,315,316,317,-1,-1,-1,-1,-1,-1,-1,-1,
  125,126,127,128,129,130,131,132,133,134,223,224,225,226,227,228,318,319,320,321,322,323,-1,-1,-1,-1,-1,-1,-1,-1,-1,-1,-1,
  16,17,18,39,40,41,135,136,137,138,139,140,141,142,143,144,229,230,231,232,233,234,264,265,324,325,326,327,328,329,-1,-1,-1,
  18,41,145,146,147,148,149,150,151,152,153,154,235,236,237,238,239,240,266,330,331,332,333,334,335,-1,-1,-1,-1,-1,-1,-1,-1,
  19,20,21,42,43,44,155,156,157,158,159,160,161,162,163,164,241,242,243,244,245,246,267,268,336,337,338,339,340,341,-1,-1,-1,
  21,44,165,166,167,168,169,170,171,172,173,174,247,248,249,250,251,252,269,342,343,344,345,346,347,-1,-1,-1,-1,-1,-1,-1,-1
};

__device__ constexpr int ADJ[NN][3] = {
  {1,9,11},{0,2,0},{1,3,6},{2,4,0},{3,5,0},{4,0,0},{2,7,0},
  {6,8,0},{7,0,0},{0,10,0},{9,0,0},{0,12,0},{11,0,0}
};
__device__ constexpr int DEG[NN] = {3,2,3,2,2,1,2,2,1,2,1,2,1};
__device__ constexpr int JM0[NJ] = {1,1,1,2,2,2,3,2,2,2,6,0,0,9,0,0,11};
__device__ constexpr int JM1[NJ] = {2,2,2,3,3,3,4,6,6,6,7,9,9,10,11,11,12};

typedef float4 F4;
using h8v = __attribute__((ext_vector_type(8))) _Float16;  // 8 fp16 (4 VGPR)
using h2v = __attribute__((ext_vector_type(2))) _Float16;  // packed half2
using f32x4  = __attribute__((ext_vector_type(4)))  float; // MFMA 16x16 C/D
using f32x16 = __attribute__((ext_vector_type(16))) float; // MFMA 32x32 C/D

// elu: for v<=0, __expf(v)-1 ~1e-7 abs err — invisible vs 0.0625 floor (R11-validated)
__device__ __forceinline__ float elu1(float v) {
  return v > 0.0f ? v : (__expf(v) - 1.0f);
}

// single-plane fp16 activations (R7-validated: absmax 0.0625 vs 0.3625 threshold)
__device__ __forceinline__ short f2h(float v) {
  _Float16 h = (_Float16)v;
  return (short)__builtin_bit_cast(unsigned short, h);
}
__device__ __forceinline__ float h2f(unsigned short s) {
  return (float)__builtin_bit_cast(_Float16, s);
}
__device__ __forceinline__ unsigned packh2(float a, float b) {
  h2v p; p.x = (_Float16)a; p.y = (_Float16)b;
  return __builtin_bit_cast(unsigned, p);
}

// A-plane LDS addressing (R8/R11-validated): phys_unit = (2*oct+half+row)&31
__device__ __forceinline__ int a_addr(int row, int col, int half) {
  const int u = (2 * (col >> 3) + half + row) & 31;
  return row * ASTRIDE + u * 8 + (col & 7);
}

// ---------------- fused pre-pass: Wmsg + W2 + (optional) W1 in ONE launch ---
// blocks 0..511:    fp16 Wmsg, frag-linear order (512 KB at ws offset 0)
// blocks 512..927:  W2 -> 16x16x32 B-fragments (416 KB at offset 131072 u32)
// blocks 928..1135: W1 -> 16x16x32 B-fragments, K padded 33->64 with zeros
//                   (208 KB at offset 237568 u32) — launched only if ws fits.
__global__ void prep_all(const float* __restrict__ Wm,
                         const float* __restrict__ W2,
                         const float* __restrict__ W1,
                         unsigned* __restrict__ ws) {
  if (blockIdx.x < 512) {
    int i = blockIdx.x * 256 + threadIdx.x;    // 0 .. 131071
    int j2   = i & 3;
    int lane = (i >> 2) & 63;
    int nt   = (i >> 8) & 3;
    int kind = (i >> 10) & 1;
    int ks   = (i >> 11) & 7;
    int l    = i >> 14;                        // 0..7
    int k = ks * 16 + ((lane >> 5) * 8) + 2 * j2;
    int n = nt * 32 + (lane & 31);
    int rbase = kind ? 128 : 0;                // bottom half of Wmsg rows = agg part
    float v0 = Wm[((l * 256) + rbase + k) * HH + n];
    float v1 = Wm[((l * 256) + rbase + k + 1) * HH + n];
    ws[i] = packh2(v0, v1);
  } else if (blockIdx.x < 928) {
    int i = (blockIdx.x - 512) * 256 + threadIdx.x;  // 0 .. 106495
    int j2   = i & 3;
    int lane = (i >> 2) & 63;
    int nt   = (i >> 8) & 7;
    int kt   = (i >> 11) & 3;
    int n    = i >> 13;                        // 0..12
    int k = kt * 32 + (lane >> 4) * 8 + 2 * j2;
    int c = nt * 16 + (lane & 15);
    float v0 = W2[(n * HH + k) * HH + c];
    float v1 = W2[(n * HH + k + 1) * HH + c];
    ws[131072 + i] = packh2(v0, v1);
  } else {
    int i = (blockIdx.x - 928) * 256 + threadIdx.x;  // 0 .. 53247
    int j2   = i & 3;
    int lane = (i >> 2) & 63;
    int nt   = (i >> 8) & 7;
    int kt   = (i >> 11) & 1;
    int n    = i >> 12;                        // 0..12
    int k = kt * 32 + (lane >> 4) * 8 + 2 * j2;
    int c = nt * 16 + (lane & 15);
    float v0 = (k     < DMAX) ? W1[(n * DMAX + k) * HH + c]     : 0.f;
    float v1 = (k + 1 < DMAX) ? W1[(n * DMAX + k + 1) * HH + c] : 0.f;
    ws[237568 + i] = packh2(v0, v1);
  }
}

// ---------------- main fused kernel (1024 thr, TB=16, 2 m-tiles/wave) -------
// R17-change vs R16 (404-418us steady): TB 8 -> 16. As doubles to 256 rows
// (128 KB; total LDS = 163840 B = the 160 KB CU max). Each wave owns m-tiles
// mq and mq+4: kp windows carry 4 independent MFMA chains (2x ILP), and all
// per-layer barrier/epilogue/staging latency is amortized over 2x elements.
// Block count halves to 1024. Phase 1/2 MFMAs now use all 16 M-rows (no pad
// waste). Accumulators are NAMED (aT0/aB0/aT1/aB1) — no runtime-indexed
// arrays (scratch rule). Phase ordering / barriers / staging unchanged.
__global__ __launch_bounds__(NTHR, 4)
void gnn_fused(const float* __restrict__ obs,
               const float* __restrict__ W1, const float* __restrict__ b1,
               const float* __restrict__ W2, const float* __restrict__ b2,
               const float* __restrict__ bm,
               const float* __restrict__ Wo, const float* __restrict__ bo,
               const float* __restrict__ wmsw,   // d_ws: [Wmsg 512K][W2 416K][W1 208K]
               float* __restrict__ out, int w1go)
{
  // A-planes: x state fp16 hi, 256 rows (elem*16+node), swizzled 16B units
  __shared__ short As[256 * ASTRIDE];      // 131072 B ; aliased as fp16 hb scratch
  __shared__ float Bb[2][4096];            // 2 x 16 KB (ks-PAIR fp16) ping-pong -> 163840 B total

  const int t    = threadIdx.x;
  const int wid  = t >> 6;        // wave 0..15
  const int mq   = wid >> 2;      // m-tile base 0..3 (wave also owns mq+4)
  const int nq   = wid & 3;       // n-quarter 0..3: cols nq*32 .. nq*32+31
  const int lane = t & 63;
  const int l31  = lane & 31;
  const int lh   = lane >> 5;     // k-half within frag / row-group bit in C
  const bool h1  = (lh == 1);
  const int g    = t >> 5;        // 32-thread group 0..31 (VALU phases)
  const int og   = t & 31;
  const int o0   = og << 2;
  const int b0   = blockIdx.x * TB;

  const F4* wsrc4 = (const F4*)wmsw;
  short* hb = As;                 // h scratch: [n(13)][row(16)][HBS shorts] = 56576 B
  short* xn16 = (short*)Bb;       // xn fp16: [n(13)][row(16)][XNS shorts] = 29952 B
  F4* bufA = (F4*)Bb;             // 1024 F4 each
  F4* bufB = ((F4*)Bb) + 1024;
  const unsigned* w2fb = ((const unsigned*)wmsw) + 131072;  // W2 fragment base
  const unsigned* w1fb = ((const unsigned*)wmsw) + 237568;  // W1 fragment base

  // ---------- Phase 0: gather xn as fp16, K padded to 64 ----------
  for (int i = t; i < TB * NN * 64; i += NTHR) {
    int d  = i & 63;
    int r  = i >> 6;
    int nn = r % NN;
    int bb = r / NN;
    int fi = (d < DMAX) ? c_feat[nn * DMAX + d] : -1;
    float v = (fi >= 0) ? obs[(b0 + bb) * OBSD + fi] : 0.0f;
    xn16[(nn * 16 + bb) * XNS + d] = f2h(v);
  }
  __syncthreads();

  // ---------- Phase 1: h = elu(xn @ W1 + b1) -> hb fp16 rows ----------------
  if (w1go) {
    // MFMA path: wave = node, 16x16x32, K=64 (2 k-tiles), 8 n-tiles. All 16
    // M-rows used (TB=16).
    if (wid < NN) {
      const int n    = wid;
      const int arow = lane & 15;
      const int kof  = (lane >> 4) * 8;
      const h8v af0 = *(const h8v*)(xn16 + (n * 16 + arow) * XNS + 0 + kof);
      const h8v af1 = *(const h8v*)(xn16 + (n * 16 + arow) * XNS + 32 + kof);
      const uint4* wf = (const uint4*)w1fb;
      const int re = (lane >> 4) * 4;     // C row base: 0,4,8,12
      #pragma unroll
      for (int nt = 0; nt < 8; ++nt) {
        f32x4 a;
        const float bias = b1[n * HH + nt * 16 + (lane & 15)];
        a[0] = bias; a[1] = bias; a[2] = bias; a[3] = bias;
        const uint4 wv0 = wf[((n * 2 + 0) * 8 + nt) * 64 + lane];
        const uint4 wv1 = wf[((n * 2 + 1) * 8 + nt) * 64 + lane];
        a = __builtin_amdgcn_mfma_f32_16x16x32_f16(af0, __builtin_bit_cast(h8v, wv0), a, 0, 0, 0);
        a = __builtin_amdgcn_mfma_f32_16x16x32_f16(af1, __builtin_bit_cast(h8v, wv1), a, 0, 0, 0);
        #pragma unroll
        for (int rg = 0; rg < 4; ++rg)
          hb[(n * 16 + re + rg) * HBS + nt * 16 + (lane & 15)] = f2h(elu1(a[rg]));
      }
    }
  } else {
    // VALU fallback (reads fp16 xn): group g -> node g>>1, 8 elems each half
    const int n  = g >> 1;         // 0..15, active < 13
    const int q0 = (g & 1) * 8;    // 8 elems per group
    if (n < NN) {
      float acc[8][4];
      const F4 bv = *(const F4*)(b1 + n * HH + o0);
      #pragma unroll
      for (int q = 0; q < 8; ++q) { acc[q][0]=bv.x; acc[q][1]=bv.y; acc[q][2]=bv.z; acc[q][3]=bv.w; }
      #pragma unroll 3
      for (int k = 0; k < DMAX; ++k) {
        const F4 w = *(const F4*)(W1 + (n * DMAX + k) * HH + o0);
        #pragma unroll
        for (int q = 0; q < 8; ++q) {
          const float xv = h2f((unsigned short)xn16[(n * 16 + q0 + q) * XNS + k]);
          acc[q][0] += xv * w.x; acc[q][1] += xv * w.y;
          acc[q][2] += xv * w.z; acc[q][3] += xv * w.w;
        }
      }
      #pragma unroll
      for (int q = 0; q < 8; ++q) {
        short4 hv;
        hv.x = f2h(elu1(acc[q][0])); hv.y = f2h(elu1(acc[q][1]));
        hv.z = f2h(elu1(acc[q][2])); hv.w = f2h(elu1(acc[q][3]));
        *(short4*)(hb + (n * 16 + (q0 + q)) * HBS + o0) = hv;
      }
    }
  }
  __syncthreads();

  // ---------- Phase 2 (MFMA): x = h @ W2 + b2, per-node 16x16x32 ------------
  f32x4 acc2[8];
  {
    if (wid < NN) {
      const int n    = wid;
      const int arow = lane & 15;
      const int kof  = (lane >> 4) * 8;
      h8v af[4];
      #pragma unroll
      for (int kt = 0; kt < 4; ++kt)
        af[kt] = *(const h8v*)(hb + (n * 16 + arow) * HBS + kt * 32 + kof);
      const uint4* wf = (const uint4*)w2fb;
      #pragma unroll
      for (int nt = 0; nt < 8; ++nt) {
        const float bias = b2[n * HH + nt * 16 + (lane & 15)];
        acc2[nt][0] = bias; acc2[nt][1] = bias;
        acc2[nt][2] = bias; acc2[nt][3] = bias;
        #pragma unroll
        for (int kt = 0; kt < 4; ++kt) {
          const uint4 wv = wf[((n * 4 + kt) * 8 + nt) * 64 + lane];
          acc2[nt] = __builtin_amdgcn_mfma_f32_16x16x32_f16(
                       af[kt], __builtin_bit_cast(h8v, wv), acc2[nt], 0, 0, 0);
        }
      }
    }
  }
  __syncthreads();   // all hb reads done; safe to overwrite As with x planes
  {
    // zero pad rows (rows elem*16+{13,14,15}); whole rows, swizzle-safe
    for (int i = t; i < 48 * HSTRIDE; i += NTHR) {
      int pr = i / HSTRIDE, off = i % HSTRIDE;
      int row = (pr / 3) * 16 + 13 + (pr % 3);
      ((int*)As)[row * HSTRIDE + off] = 0;
    }
    if (wid < NN) {
      const int n  = wid;
      const int e0 = (lane >> 4) * 4;     // C row base: 0,4,8,12 — all valid
      #pragma unroll
      for (int nt = 0; nt < 8; ++nt) {
        const int col = nt * 16 + (lane & 15);
        #pragma unroll
        for (int rg = 0; rg < 4; ++rg) {
          const int row = (e0 + rg) * 16 + n;
          As[a_addr(row, col, 0)] = f2h(acc2[nt][rg]);
        }
      }
    }
  }
  __syncthreads();

  // ---------- Phase 3: 8 MFMA layers (2 m-tiles/wave, depth-2 prefetch) -----
  {
    // prologue: stage pair 0 to LDS; prefetch pair 1 into regs
    bufA[t] = wsrc4[t];
    F4 rnext = wsrc4[1024 + t];
    __syncthreads();

    #pragma unroll 1
    for (int l = 0; l < NL; ++l) {
      f32x16 aT0, aB0, aT1, aB1;
      #pragma unroll
      for (int r = 0; r < 16; ++r) {
        aT0[r] = 0.f; aB0[r] = 0.f; aT1[r] = 0.f; aB1[r] = 0.f;
      }

      #pragma unroll 1
      for (int kp = 0; kp < 4; ++kp) {
        const int gpc = l * 4 + kp;          // global pair index 0..31
        F4* cur = (gpc & 1) ? bufB : bufA;
        F4* nxt = (gpc & 1) ? bufA : bufB;

        F4 rnext2;
        const bool more2 = (gpc + 2 < NL * 4);
        if (more2) rnext2 = wsrc4[(size_t)(gpc + 2) * 1024 + t];

        #pragma unroll
        for (int kk = 0; kk < 2; ++kk) {
          const int ks = kp * 2 + kk;
          // 8 KB sub-chunk = 4096 shorts
          const short* bb = ((const short*)cur) + kk * 4096;

          const int p = 2 * ks + lh;           // oct index 0..15
          const int row0 = mq * 32 + l31;
          const int row1 = (mq + 4) * 32 + l31;
          const h8v ah0 = *(const h8v*)(As + row0 * ASTRIDE + (((2 * p + row0) & 31) * 8));
          const h8v ah1 = *(const h8v*)(As + row1 * ASTRIDE + (((2 * p + row1) & 31) * 8));
          const h8v bth = *(const h8v*)(bb + ((0 * 4 + nq) * 64 + lane) * 8);
          const h8v bbh = *(const h8v*)(bb + ((1 * 4 + nq) * 64 + lane) * 8);

          aT0 = __builtin_amdgcn_mfma_f32_32x32x16_f16(ah0, bth, aT0, 0, 0, 0);
          aB0 = __builtin_amdgcn_mfma_f32_32x32x16_f16(ah0, bbh, aB0, 0, 0, 0);
          aT1 = __builtin_amdgcn_mfma_f32_32x32x16_f16(ah1, bth, aT1, 0, 0, 0);
          aB1 = __builtin_amdgcn_mfma_f32_32x32x16_f16(ah1, bbh, aB1, 0, 0, 0);
        }

        if (gpc + 1 < NL * 4) nxt[t] = rnext;  // write pair gpc+1 (loaded last window)
        __syncthreads();   // publishes nxt; guards cur reuse and A-row overwrite
        rnext = rnext2;
      }

      // epilogue per m-tile: x_new = elu(Y_top + N*Y_bot + bias) -> As
      {
        const int col  = nq * 32 + l31;
        const float bias = bm[l * HH + col];

        #define EPILOG(AT, AB, MQB)                                          \
        {                                                                    \
          float cb[16], sw[16];                                              \
          _Pragma("unroll")                                                  \
          for (int r = 0; r < 16; ++r) { cb[r] = (AB)[r];                    \
                                         sw[r] = __shfl_xor(cb[r], 32); }    \
          _Pragma("unroll")                                                  \
          for (int r = 0; r < 16; ++r) {                                     \
            const int p  = (r & 3) + 8 * (r >> 2);                           \
            const int n0 = p & 15;                                           \
            const int n1 = n0 + 4;                                           \
            const int es = p >> 4;                                           \
            float a0, a1 = 0.f;                                              \
            {                                                                \
              const int np0 = ADJ[n0][0];                                    \
              const int rl0 = (es << 4) + np0;                               \
              const int hp0 = (rl0 >> 2) & 1;                                \
              const int pp0 = rl0 - 4 * hp0;                                 \
              const int rp0 = (pp0 & 3) + 4 * (pp0 >> 3);                    \
              a0 = (hp0 == 1) ? (h1 ? cb[rp0] : sw[rp0])                     \
                              : (h1 ? sw[rp0] : cb[rp0]);                    \
              if (DEG[n0] > 1) {                                             \
                const int np = ADJ[n0][1];                                   \
                const int rl = (es << 4) + np;                               \
                const int hp = (rl >> 2) & 1;                                \
                const int pp = rl - 4 * hp;                                  \
                const int rp = (pp & 3) + 4 * (pp >> 3);                     \
                a0 += (hp == 1) ? (h1 ? cb[rp] : sw[rp])                     \
                                : (h1 ? sw[rp] : cb[rp]);                    \
              }                                                              \
              if (DEG[n0] > 2) {                                             \
                const int np = ADJ[n0][2];                                   \
                const int rl = (es << 4) + np;                               \
                const int hp = (rl >> 2) & 1;                                \
                const int pp = rl - 4 * hp;                                  \
                const int rp = (pp & 3) + 4 * (pp >> 3);                     \
                a0 += (hp == 1) ? (h1 ? cb[rp] : sw[rp])                     \
                                : (h1 ? sw[rp] : cb[rp]);                    \
              }                                                              \
            }                                                                \
            if (n1 < NN) {                                                   \
              const int np0 = ADJ[n1][0];                                    \
              const int rl0 = (es << 4) + np0;                               \
              const int hp0 = (rl0 >> 2) & 1;                                \
              const int pp0 = rl0 - 4 * hp0;                                 \
              const int rp0 = (pp0 & 3) + 4 * (pp0 >> 3);                    \
              a1 = (hp0 == 1) ? (h1 ? cb[rp0] : sw[rp0])                     \
                              : (h1 ? sw[rp0] : cb[rp0]);                    \
              if (DEG[n1] > 1) {                                             \
                const int np = ADJ[n1][1];                                   \
                const int rl = (es << 4) + np;                               \
                const int hp = (rl >> 2) & 1;                                \
                const int pp = rl - 4 * hp;                                  \
                const int rp = (pp & 3) + 4 * (pp >> 3);                     \
                a1 += (hp == 1) ? (h1 ? cb[rp] : sw[rp])                     \
                                : (h1 ? sw[rp] : cb[rp]);                    \
              }                                                              \
              if (DEG[n1] > 2) {                                             \
                const int np = ADJ[n1][2];                                   \
                const int rl = (es << 4) + np;                               \
                const int hp = (rl >> 2) & 1;                                \
                const int pp = rl - 4 * hp;                                  \
                const int rp = (pp & 3) + 4 * (pp >> 3);                     \
                a1 += (hp == 1) ? (h1 ? cb[rp] : sw[rp])                     \
                                : (h1 ? sw[rp] : cb[rp]);                    \
              }                                                              \
            }                                                                \
            const float agg = h1 ? a1 : a0;                                  \
            const float tot = (AT)[r] + agg + bias;                          \
            float xv = elu1(tot);                                            \
            if (n1 >= NN) xv = h1 ? 0.f : xv;                                \
            const int row = (MQB) * 32 + p + 4 * lh;                         \
            As[a_addr(row, col, 0)] = f2h(xv);                               \
          }                                                                  \
        }

        EPILOG(aT0, aB0, mq)
        EPILOG(aT1, aB1, (mq + 4))
        #undef EPILOG
      }
      __syncthreads();
    }
  }

  // ---------- Phase 4: readout ----------------------------------------------
  if (g < TB) {
    const int elem = g;          // 0..15
    const int c = og * 4;        // 4 channels per thread
    float xv[NN][4];
    #pragma unroll
    for (int n = 0; n < NN; ++n) {
      const int row = elem * 16 + n;
      const ushort4 uh = *(const ushort4*)(As + a_addr(row, c, 0));
      xv[n][0] = h2f(uh.x);
      xv[n][1] = h2f(uh.y);
      xv[n][2] = h2f(uh.z);
      xv[n][3] = h2f(uh.w);
    }
    #pragma unroll
    for (int j = 0; j < NJ; ++j) {
      const F4 wa = *(const F4*)(Wo + j * 256 + c);
      const F4 wb = *(const F4*)(Wo + j * 256 + 128 + c);
      const float* xa = xv[JM0[j]];
      const float* xb = xv[JM1[j]];
      float p = xa[0]*wa.x + xa[1]*wa.y + xa[2]*wa.z + xa[3]*wa.w
              + xb[0]*wb.x + xb[1]*wb.y + xb[2]*wb.z + xb[3]*wb.w;
      p += __shfl_xor(p, 16);
      p += __shfl_xor(p, 8);
      p += __shfl_xor(p, 4);
      p += __shfl_xor(p, 2);
      p += __shfl_xor(p, 1);
      if (og == 0) out[(b0 + elem) * NJ + j] = p + bo[j];
    }
  }
}

extern "C" void kernel_launch(void* const* d_in, const int* in_sizes, int n_in,
                              void* d_out, int out_size, void* d_ws, size_t ws_size,
                              hipStream_t stream) {
  const float* obs = (const float*)d_in[0];
  const float* W1  = (const float*)d_in[1];
  const float* b1  = (const float*)d_in[2];
  const float* W2  = (const float*)d_in[3];
  const float* b2  = (const float*)d_in[4];
  const float* Wm  = (const float*)d_in[5];
  const float* bm  = (const float*)d_in[6];
  const float* Wo  = (const float*)d_in[7];
  const float* bo  = (const float*)d_in[8];
  float* out = (float*)d_out;

  const int B = in_sizes[0] / OBSD;   // 16384
  const int nblk = B / TB;            // 1024

  // ws need: Wmsg 131072 + W2 106496 + W1 53248 u32 = 1,163,264 B
  const size_t need = (size_t)(131072 + 106496 + 53248) * 4;
  const int w1go = (ws_size >= need) ? 1 : 0;

  // fused pre-pass (W1 fragment blocks launched only when they fit in ws)
  prep_all<<<w1go ? 1136 : 928, 256, 0, stream>>>(Wm, W2, W1, (unsigned*)d_ws);
  gnn_fused<<<nblk, NTHR, 0, stream>>>(obs, W1, b1, W2, b2, bm, Wo, bo,
                                       (const float*)d_ws, out, w1go);
}